// Round 2
// baseline (3058.257 us; speedup 1.0000x reference)
//
#include <hip/hip_runtime.h>
#include <hip/hip_bf16.h>
#include <cstdint>

typedef unsigned short u16;
typedef unsigned int   u32;
typedef __attribute__((ext_vector_type(8))) short bf16x8;  // 8 bf16 = 4 VGPRs
typedef __attribute__((ext_vector_type(4))) float f32x4;

__device__ __forceinline__ float bf2f(u16 u) {
    union { u32 i; float f; } c; c.i = ((u32)u) << 16; return c.f;
}
__device__ __forceinline__ u16 f2bf(float f) {
    union { float f; u32 i; } c; c.f = f;
    u32 x = c.i;
    return (u16)((x + 0x7fffu + ((x >> 16) & 1u)) >> 16);  // RNE
}
__device__ __forceinline__ void atomAddF(float* p, float v) {
    unsafeAtomicAdd(p, v);  // global_atomic_add_f32, not a CAS loop
}
__device__ __forceinline__ float sigmoidf(float x) {
    return 1.0f / (1.0f + __expf(-x));
}

// ---------------------------------------------------------------------------
// fp32 -> bf16 elementwise cast (x into bufX)
__global__ void cast_f2b(const float* __restrict__ A, u16* __restrict__ B, int n4) {
    int i  = blockIdx.x * blockDim.x + threadIdx.x;
    int st = gridDim.x * blockDim.x;
    for (; i < n4; i += st) {
        float4 a = ((const float4*)A)[i];
        ushort4 o;
        o.x = f2bf(a.x); o.y = f2bf(a.y); o.z = f2bf(a.z); o.w = f2bf(a.w);
        ((ushort4*)B)[i] = o;
    }
}

// ---------------------------------------------------------------------------
// Transpose+cast the 4+4 128x128 fp32 weight matrices once: Wt[n][k] = bf16(W[k][n])
struct P8 { const float* p[8]; };
__global__ void transpose_w(P8 wsrc, u16* __restrict__ Wt) {
    const float* W = wsrc.p[blockIdx.x];
    u16* T = Wt + (size_t)blockIdx.x * 16384;
    int t = threadIdx.x;  // 256 threads
    for (int p = 0; p < 64; ++p) {
        int idx = p * 256 + t;
        int k = idx >> 7, n = idx & 127;
        T[n * 128 + k] = f2bf(W[k * 128 + n]);
    }
}

// ---------------------------------------------------------------------------
// Fused GEMM: for one layer (Dout=128) compute
//   K = x@Wk, Q = x@Wq, V = x@Wv  (bf16 out)
//   AGG = x@Ws + b                (fp32 out; becomes the scatter accumulator)
// Block: 256 thr (4 waves), 128-row tile. Wave w owns rows [w*32, w*32+32).
#define XS 136  // 128 + 8 pad -> 2-way LDS bank aliasing (free per m136)
__global__ __launch_bounds__(256, 2)
void gemm_kqvs(const u16* __restrict__ X, const u16* __restrict__ Wt,
               const float* __restrict__ bias,
               u16* __restrict__ K, u16* __restrict__ Q, u16* __restrict__ V,
               float* __restrict__ AGG, int nrows)
{
    __shared__ u16 xs[128 * XS];
    __shared__ u16 wsl[128 * XS];
    const int tid  = threadIdx.x;
    const int wave = tid >> 6, lane = tid & 63;
    const int quad = lane >> 4, l16 = lane & 15;
    const int r0 = blockIdx.x * 128;

    // stage X tile (128x128 bf16) via 16B chunks, 8 per thread
    for (int p = 0; p < 8; ++p) {
        int c = p * 256 + tid;
        int row = c >> 4;
        int col = (c & 15) * 8;
        int gr = r0 + row; if (gr >= nrows) gr = nrows - 1;  // clamp tail (stores predicated)
        uint4 d = *(const uint4*)(X + (size_t)gr * 128 + col);
        *(uint4*)(&xs[row * XS + col]) = d;
    }

    for (int wi = 0; wi < 4; ++wi) {
        __syncthreads();  // protects wsl from previous iter's readers
        const u16* Wsrc = Wt + wi * (128 * 128);
        for (int p = 0; p < 8; ++p) {
            int c = p * 256 + tid;
            int row = c >> 4;
            int col = (c & 15) * 8;
            uint4 d = *(const uint4*)(Wsrc + row * 128 + col);
            *(uint4*)(&wsl[row * XS + col]) = d;
        }
        __syncthreads();

        f32x4 acc[2][8];
        for (int mt = 0; mt < 2; ++mt)
            for (int nt = 0; nt < 8; ++nt) acc[mt][nt] = (f32x4)0.0f;

        const int rbase = wave * 32;
        for (int kt = 0; kt < 4; ++kt) {
            // A[m = l16][k = quad*8 + j] (verified layout, guide §3)
            bf16x8 a0 = *(const bf16x8*)&xs[(rbase + l16)      * XS + kt * 32 + quad * 8];
            bf16x8 a1 = *(const bf16x8*)&xs[(rbase + 16 + l16) * XS + kt * 32 + quad * 8];
            for (int nt = 0; nt < 8; ++nt) {
                // B[k = quad*8 + j][n = l16] <- Wt[n][k] rows contiguous
                bf16x8 b = *(const bf16x8*)&wsl[(nt * 16 + l16) * XS + kt * 32 + quad * 8];
                acc[0][nt] = __builtin_amdgcn_mfma_f32_16x16x32_bf16(a0, b, acc[0][nt], 0, 0, 0);
                acc[1][nt] = __builtin_amdgcn_mfma_f32_16x16x32_bf16(a1, b, acc[1][nt], 0, 0, 0);
            }
        }

        // epilogue: C/D layout col = l16, row = quad*4 + r (verified, guide §3)
        for (int mt = 0; mt < 2; ++mt) {
            int growb = r0 + rbase + mt * 16 + quad * 4;
            for (int r = 0; r < 4; ++r) {
                int grow = growb + r;
                if (grow >= nrows) continue;
                for (int nt = 0; nt < 8; ++nt) {
                    int col = nt * 16 + l16;
                    float vv = acc[mt][nt][r];
                    size_t o = (size_t)grow * 128 + col;
                    if      (wi == 0) K[o] = f2bf(vv);
                    else if (wi == 1) Q[o] = f2bf(vv);
                    else if (wi == 2) V[o] = f2bf(vv);
                    else              AGG[o] = vv + bias[col];
                }
            }
        }
    }
}

// ---------------------------------------------------------------------------
// Edge phase, Dout=128: wave per edge, lane owns channels {2*lane, 2*lane+1}.
// AGG[dst] += sigmoid(K[dst]+Q[src]) * V[src]
__global__ __launch_bounds__(256)
void edge128(const int* __restrict__ src, const int* __restrict__ dst,
             const u16* __restrict__ K, const u16* __restrict__ Q,
             const u16* __restrict__ V, float* __restrict__ AGG, int nE)
{
    int lane = threadIdx.x & 63;
    int gw = blockIdx.x * (blockDim.x >> 6) + (threadIdx.x >> 6);
    int nw = gridDim.x * (blockDim.x >> 6);
    int c2 = lane * 2;
    for (int e = gw; e < nE; e += nw) {
        int s = src[e], d = dst[e];
        u32 kk = *(const u32*)(K + (size_t)d * 128 + c2);
        u32 qq = *(const u32*)(Q + (size_t)s * 128 + c2);
        u32 vv = *(const u32*)(V + (size_t)s * 128 + c2);
        float z0 = bf2f((u16)kk) + bf2f((u16)qq);
        float z1 = bf2f((u16)(kk >> 16)) + bf2f((u16)(qq >> 16));
        float m0 = sigmoidf(z0) * bf2f((u16)vv);
        float m1 = sigmoidf(z1) * bf2f((u16)(vv >> 16));
        float* a = AGG + (size_t)d * 128 + c2;
        atomAddF(a,     m0);
        atomAddF(a + 1, m1);
    }
}

// ---------------------------------------------------------------------------
__global__ void relu_cast(const float* __restrict__ A, u16* __restrict__ Xo, int n4) {
    int i  = blockIdx.x * blockDim.x + threadIdx.x;
    int st = gridDim.x * blockDim.x;
    for (; i < n4; i += st) {
        float4 a = ((const float4*)A)[i];
        ushort4 o;
        o.x = f2bf(fmaxf(a.x, 0.0f));
        o.y = f2bf(fmaxf(a.y, 0.0f));
        o.z = f2bf(fmaxf(a.z, 0.0f));
        o.w = f2bf(fmaxf(a.w, 0.0f));
        ((ushort4*)Xo)[i] = o;
    }
}

// ---------------------------------------------------------------------------
// Layer 3 (Dout=1): 4 GEMVs, wave per node, shuffle reduce. Weights fp32.
// Writes the skip term (x@Ws + b) DIRECTLY into d_out (full coverage -> the
// 0xAA re-poison is always overwritten), k3/q3/v3 into ws scratch.
__global__ __launch_bounds__(256)
void gemv3(const u16* __restrict__ X,
           const float* __restrict__ Wk, const float* __restrict__ Wq,
           const float* __restrict__ Wv, const float* __restrict__ Ws,
           const float* __restrict__ b3,
           float* __restrict__ k3, float* __restrict__ q3,
           float* __restrict__ v3, float* __restrict__ outp, int N)
{
    int lane = threadIdx.x & 63;
    int gw = blockIdx.x * (blockDim.x >> 6) + (threadIdx.x >> 6);
    int nw = gridDim.x * (blockDim.x >> 6);
    int c2 = lane * 2;
    float2 wk = *(const float2*)(Wk + c2);
    float2 wq = *(const float2*)(Wq + c2);
    float2 wv = *(const float2*)(Wv + c2);
    float2 ws = *(const float2*)(Ws + c2);
    float bias = b3[0];
    for (int i = gw; i < N; i += nw) {
        u32 xx = *(const u32*)(X + (size_t)i * 128 + c2);
        float x0 = bf2f((u16)xx), x1 = bf2f((u16)(xx >> 16));
        float pk = x0 * wk.x + x1 * wk.y;
        float pq = x0 * wq.x + x1 * wq.y;
        float pv = x0 * wv.x + x1 * wv.y;
        float ps = x0 * ws.x + x1 * ws.y;
        for (int off = 32; off > 0; off >>= 1) {
            pk += __shfl_xor(pk, off);
            pq += __shfl_xor(pq, off);
            pv += __shfl_xor(pv, off);
            ps += __shfl_xor(ps, off);
        }
        if (lane == 0) { k3[i] = pk; q3[i] = pq; v3[i] = pv; outp[i] = ps + bias; }
    }
}

__global__ void edge3(const int* __restrict__ src, const int* __restrict__ dst,
                      const float* __restrict__ k3, const float* __restrict__ q3,
                      const float* __restrict__ v3, float* __restrict__ outp, int nE)
{
    int i  = blockIdx.x * blockDim.x + threadIdx.x;
    int st = gridDim.x * blockDim.x;
    for (; i < nE; i += st) {
        int s = src[i], d = dst[i];
        float g = sigmoidf(k3[d] + q3[s]);
        atomAddF(outp + d, g * v3[s]);
    }
}

// ---------------------------------------------------------------------------
extern "C" void kernel_launch(void* const* d_in, const int* in_sizes, int n_in,
                              void* d_out, int out_size, void* d_ws, size_t ws_size,
                              hipStream_t stream)
{
    const float* x0 = (const float*)d_in[0];
    const int*   ei = (const int*)d_in[1];
    const int    N  = in_sizes[0] / 128;   // 100000
    const int    E  = in_sizes[1] / 2;     // 1600000
    const int* src = ei;
    const int* dst = ei + E;

    char* ws = (char*)d_ws;
    size_t off = 0;
    auto carve = [&](size_t bytes) { void* p = ws + off; off += (bytes + 255) & ~(size_t)255; return p; };
    u16*   Wt   = (u16*)  carve((size_t)8 * 16384 * sizeof(u16));
    u16*   bufX = (u16*)  carve((size_t)N * 128 * sizeof(u16));
    u16*   bufK = (u16*)  carve((size_t)N * 128 * sizeof(u16));
    u16*   bufQ = (u16*)  carve((size_t)N * 128 * sizeof(u16));
    u16*   bufV = (u16*)  carve((size_t)N * 128 * sizeof(u16));
    float* bufA = (float*)carve((size_t)N * 128 * sizeof(float));
    // layer-3 scalars reuse bufK (dead by then)
    float* k3 = (float*)bufK;
    float* q3 = k3 + N;
    float* v3 = q3 + N;

    P8 wp;
    wp.p[0] = (const float*)d_in[2];  wp.p[1] = (const float*)d_in[3];
    wp.p[2] = (const float*)d_in[4];  wp.p[3] = (const float*)d_in[5];
    wp.p[4] = (const float*)d_in[7];  wp.p[5] = (const float*)d_in[8];
    wp.p[6] = (const float*)d_in[9];  wp.p[7] = (const float*)d_in[10];
    transpose_w<<<8, 256, 0, stream>>>(wp, Wt);
    cast_f2b<<<1024, 256, 0, stream>>>(x0, bufX, N * 128 / 4);

    int gb = (N + 127) / 128;

    // layer 1
    gemm_kqvs<<<gb, 256, 0, stream>>>(bufX, Wt, (const float*)d_in[6], bufK, bufQ, bufV, bufA, N);
    edge128<<<2048, 256, 0, stream>>>(src, dst, bufK, bufQ, bufV, bufA, E);
    relu_cast<<<1024, 256, 0, stream>>>(bufA, bufX, N * 128 / 4);
    // layer 2
    gemm_kqvs<<<gb, 256, 0, stream>>>(bufX, Wt + 4 * 16384, (const float*)d_in[11], bufK, bufQ, bufV, bufA, N);
    edge128<<<2048, 256, 0, stream>>>(src, dst, bufK, bufQ, bufV, bufA, E);
    relu_cast<<<1024, 256, 0, stream>>>(bufA, bufX, N * 128 / 4);
    // layer 3 (Dout=1)
    gemv3<<<512, 256, 0, stream>>>(bufX,
        (const float*)d_in[12], (const float*)d_in[13], (const float*)d_in[14],
        (const float*)d_in[15], (const float*)d_in[16],
        k3, q3, v3, (float*)d_out, N);
    edge3<<<1024, 256, 0, stream>>>(src, dst, k3, q3, v3, (float*)d_out, E);
}

// Round 3
// 1012.438 us; speedup vs baseline: 3.0207x; 3.0207x over previous
//
#include <hip/hip_runtime.h>
#include <hip/hip_bf16.h>
#include <cstdint>

typedef unsigned short u16;
typedef unsigned int   u32;
typedef __attribute__((ext_vector_type(8))) short bf16x8;  // 8 bf16 = 4 VGPRs
typedef __attribute__((ext_vector_type(4))) float f32x4;

__device__ __forceinline__ float bf2f(u16 u) {
    union { u32 i; float f; } c; c.i = ((u32)u) << 16; return c.f;
}
__device__ __forceinline__ u16 f2bf(float f) {
    union { float f; u32 i; } c; c.f = f;
    u32 x = c.i;
    return (u16)((x + 0x7fffu + ((x >> 16) & 1u)) >> 16);  // RNE
}
__device__ __forceinline__ float sigmoidf(float x) {
    return 1.0f / (1.0f + __expf(-x));
}

// ---------------------------------------------------------------------------
// fp32 -> bf16 elementwise cast (x into bufX)
__global__ void cast_f2b(const float* __restrict__ A, u16* __restrict__ B, int n4) {
    int i  = blockIdx.x * blockDim.x + threadIdx.x;
    int st = gridDim.x * blockDim.x;
    for (; i < n4; i += st) {
        float4 a = ((const float4*)A)[i];
        ushort4 o;
        o.x = f2bf(a.x); o.y = f2bf(a.y); o.z = f2bf(a.z); o.w = f2bf(a.w);
        ((ushort4*)B)[i] = o;
    }
}

// ---------------------------------------------------------------------------
// Transpose+cast the 4+4 128x128 fp32 weight matrices once: Wt[n][k] = bf16(W[k][n])
struct P8 { const float* p[8]; };
__global__ void transpose_w(P8 wsrc, u16* __restrict__ Wt) {
    const float* W = wsrc.p[blockIdx.x];
    u16* T = Wt + (size_t)blockIdx.x * 16384;
    int t = threadIdx.x;  // 256 threads
    for (int p = 0; p < 64; ++p) {
        int idx = p * 256 + t;
        int k = idx >> 7, n = idx & 127;
        T[n * 128 + k] = f2bf(W[k * 128 + n]);
    }
}

// ---------------------------------------------------------------------------
// CSR build: histogram -> single-block scan -> scatter
__global__ void hist_k(const int* __restrict__ dst, int* __restrict__ deg, int nE) {
    int i  = blockIdx.x * blockDim.x + threadIdx.x;
    int st = gridDim.x * blockDim.x;
    for (; i < nE; i += st) atomicAdd(&deg[dst[i]], 1);
}

__global__ __launch_bounds__(1024)
void scan_k(const int* __restrict__ deg, int* __restrict__ row_ptr, int N, int Etot) {
    __shared__ int part[1024];
    int t = threadIdx.x;
    int chunk = (N + 1023) >> 10;
    int beg = t * chunk, end = min(beg + chunk, N);
    int s = 0;
    for (int i = beg; i < end; ++i) s += deg[i];
    part[t] = s;
    __syncthreads();
    for (int off = 1; off < 1024; off <<= 1) {
        int v = (t >= off) ? part[t - off] : 0;
        __syncthreads();
        part[t] += v;
        __syncthreads();
    }
    int run = (t == 0) ? 0 : part[t - 1];
    for (int i = beg; i < end; ++i) { row_ptr[i] = run; run += deg[i]; }
    if (t == 1023) row_ptr[N] = Etot;
}

__global__ void scatter_k(const int* __restrict__ src, const int* __restrict__ dst,
                          const int* __restrict__ row_ptr, int* __restrict__ cur,
                          int* __restrict__ ssrc, int nE) {
    int i  = blockIdx.x * blockDim.x + threadIdx.x;
    int st = gridDim.x * blockDim.x;
    for (; i < nE; i += st) {
        int d = dst[i];
        int pos = row_ptr[d] + atomicAdd(&cur[d], 1);
        ssrc[pos] = src[i];
    }
}

// ---------------------------------------------------------------------------
// Fused GEMM: K = x@Wk, Q = x@Wq, V = x@Wv, S = x@Ws + b  (all bf16 out)
//   KS[node][0..127]   = K row     (read per-dst, sequential)
//   KS[node][128..255] = S row
//   QV[node][p*4+{0,1}] = Q[2p],Q[2p+1]; QV[node][p*4+{2,3}] = V[2p],V[2p+1]
//   (one 512B dwordx2 wave-load per src gather in the edge phase)
#define XS 136  // 128 + 8 pad -> 2-way LDS bank aliasing (free per m136)
__global__ __launch_bounds__(256, 2)
void gemm_kqvs(const u16* __restrict__ X, const u16* __restrict__ Wt,
               const float* __restrict__ bias,
               u16* __restrict__ KS, u16* __restrict__ QV, int nrows)
{
    __shared__ u16 xs[128 * XS];
    __shared__ u16 wsl[128 * XS];
    const int tid  = threadIdx.x;
    const int wave = tid >> 6, lane = tid & 63;
    const int quad = lane >> 4, l16 = lane & 15;
    const int r0 = blockIdx.x * 128;

    for (int p = 0; p < 8; ++p) {
        int c = p * 256 + tid;
        int row = c >> 4;
        int col = (c & 15) * 8;
        int gr = r0 + row; if (gr >= nrows) gr = nrows - 1;
        uint4 d = *(const uint4*)(X + (size_t)gr * 128 + col);
        *(uint4*)(&xs[row * XS + col]) = d;
    }

    for (int wi = 0; wi < 4; ++wi) {
        __syncthreads();
        const u16* Wsrc = Wt + wi * (128 * 128);
        for (int p = 0; p < 8; ++p) {
            int c = p * 256 + tid;
            int row = c >> 4;
            int col = (c & 15) * 8;
            uint4 d = *(const uint4*)(Wsrc + row * 128 + col);
            *(uint4*)(&wsl[row * XS + col]) = d;
        }
        __syncthreads();

        f32x4 acc[2][8];
        for (int mt = 0; mt < 2; ++mt)
            for (int nt = 0; nt < 8; ++nt) acc[mt][nt] = (f32x4)0.0f;

        const int rbase = wave * 32;
        for (int kt = 0; kt < 4; ++kt) {
            bf16x8 a0 = *(const bf16x8*)&xs[(rbase + l16)      * XS + kt * 32 + quad * 8];
            bf16x8 a1 = *(const bf16x8*)&xs[(rbase + 16 + l16) * XS + kt * 32 + quad * 8];
            for (int nt = 0; nt < 8; ++nt) {
                bf16x8 b = *(const bf16x8*)&wsl[(nt * 16 + l16) * XS + kt * 32 + quad * 8];
                acc[0][nt] = __builtin_amdgcn_mfma_f32_16x16x32_bf16(a0, b, acc[0][nt], 0, 0, 0);
                acc[1][nt] = __builtin_amdgcn_mfma_f32_16x16x32_bf16(a1, b, acc[1][nt], 0, 0, 0);
            }
        }

        for (int mt = 0; mt < 2; ++mt) {
            int growb = r0 + rbase + mt * 16 + quad * 4;
            for (int r = 0; r < 4; ++r) {
                int grow = growb + r;
                if (grow >= nrows) continue;
                for (int nt = 0; nt < 8; ++nt) {
                    int col = nt * 16 + l16;
                    float vv = acc[mt][nt][r];
                    size_t nb = (size_t)grow * 256;
                    if      (wi == 0) KS[nb + col] = f2bf(vv);
                    else if (wi == 3) KS[nb + 128 + col] = f2bf(vv + bias[col]);
                    else if (wi == 1) QV[nb + (col >> 1) * 4 + (col & 1)] = f2bf(vv);
                    else              QV[nb + (col >> 1) * 4 + 2 + (col & 1)] = f2bf(vv);
                }
            }
        }
    }
}

// ---------------------------------------------------------------------------
// CSR gather-reduce edge phase (layers 1,2): one wave per dst node.
//   out[d] = relu( S[d] + sum_{s in adj(d)} sigmoid(K[d]+Q[s]) * V[s] )  (bf16)
// Zero atomics; one coalesced 512B gather per edge; one 256B write per node.
__global__ __launch_bounds__(256)
void edge_csr(const int* __restrict__ row_ptr, const int* __restrict__ ssrc,
              const u16* __restrict__ KS, const u16* __restrict__ QV,
              u16* __restrict__ Xout, int N)
{
    int lane = threadIdx.x & 63;
    int gw = blockIdx.x * (blockDim.x >> 6) + (threadIdx.x >> 6);
    int nw = gridDim.x * (blockDim.x >> 6);
    int c2 = lane * 2;
    for (int d = gw; d < N; d += nw) {
        int beg = row_ptr[d], end = row_ptr[d + 1];
        u32 kk = *(const u32*)(KS + (size_t)d * 256 + c2);
        float k0 = bf2f((u16)kk), k1 = bf2f((u16)(kk >> 16));
        float a0 = 0.0f, a1 = 0.0f;
        for (int base = beg; base < end; base += 64) {
            int e = base + lane;
            int s = (e < end) ? ssrc[e] : 0;
            int m = end - base; if (m > 64) m = 64;
            for (int j = 0; j < m; ++j) {
                int sj = __shfl(s, j);
                uint2 qv = *(const uint2*)(QV + (size_t)sj * 256 + lane * 4);
                float q0 = bf2f((u16)qv.x), q1 = bf2f((u16)(qv.x >> 16));
                float v0 = bf2f((u16)qv.y), v1 = bf2f((u16)(qv.y >> 16));
                a0 += sigmoidf(k0 + q0) * v0;
                a1 += sigmoidf(k1 + q1) * v1;
            }
        }
        u32 ss = *(const u32*)(KS + (size_t)d * 256 + 128 + c2);
        float r0 = fmaxf(bf2f((u16)ss) + a0, 0.0f);
        float r1 = fmaxf(bf2f((u16)(ss >> 16)) + a1, 0.0f);
        *(u32*)(Xout + (size_t)d * 128 + c2) = ((u32)f2bf(r1) << 16) | f2bf(r0);
    }
}

// ---------------------------------------------------------------------------
// Layer 3 (Dout=1): 4 GEMVs, wave per node, shuffle reduce. Weights fp32.
__global__ __launch_bounds__(256)
void gemv3(const u16* __restrict__ X,
           const float* __restrict__ Wk, const float* __restrict__ Wq,
           const float* __restrict__ Wv, const float* __restrict__ Ws,
           const float* __restrict__ b3,
           float* __restrict__ k3, float* __restrict__ q3,
           float* __restrict__ v3, float* __restrict__ s3, int N)
{
    int lane = threadIdx.x & 63;
    int gw = blockIdx.x * (blockDim.x >> 6) + (threadIdx.x >> 6);
    int nw = gridDim.x * (blockDim.x >> 6);
    int c2 = lane * 2;
    float2 wk = *(const float2*)(Wk + c2);
    float2 wq = *(const float2*)(Wq + c2);
    float2 wv = *(const float2*)(Wv + c2);
    float2 ws = *(const float2*)(Ws + c2);
    float bias = b3[0];
    for (int i = gw; i < N; i += nw) {
        u32 xx = *(const u32*)(X + (size_t)i * 128 + c2);
        float x0 = bf2f((u16)xx), x1 = bf2f((u16)(xx >> 16));
        float pk = x0 * wk.x + x1 * wk.y;
        float pq = x0 * wq.x + x1 * wq.y;
        float pv = x0 * wv.x + x1 * wv.y;
        float ps = x0 * ws.x + x1 * ws.y;
        for (int off = 32; off > 0; off >>= 1) {
            pk += __shfl_xor(pk, off);
            pq += __shfl_xor(pq, off);
            pv += __shfl_xor(pv, off);
            ps += __shfl_xor(ps, off);
        }
        if (lane == 0) { k3[i] = pk; q3[i] = pq; v3[i] = pv; s3[i] = ps + bias; }
    }
}

// CSR edge phase, Dout=1: wave per node, lanes stride edges, butterfly reduce.
__global__ __launch_bounds__(256)
void edge3_csr(const int* __restrict__ row_ptr, const int* __restrict__ ssrc,
               const float* __restrict__ k3, const float* __restrict__ q3,
               const float* __restrict__ v3, const float* __restrict__ s3,
               float* __restrict__ outp, int N)
{
    int lane = threadIdx.x & 63;
    int gw = blockIdx.x * (blockDim.x >> 6) + (threadIdx.x >> 6);
    int nw = gridDim.x * (blockDim.x >> 6);
    for (int d = gw; d < N; d += nw) {
        int beg = row_ptr[d], end = row_ptr[d + 1];
        float kd = k3[d];
        float sum = 0.0f;
        for (int e = beg + lane; e < end; e += 64) {
            int s = ssrc[e];
            sum += sigmoidf(kd + q3[s]) * v3[s];
        }
        for (int off = 32; off > 0; off >>= 1) sum += __shfl_xor(sum, off);
        if (lane == 0) outp[d] = s3[d] + sum;
    }
}

// ---------------------------------------------------------------------------
extern "C" void kernel_launch(void* const* d_in, const int* in_sizes, int n_in,
                              void* d_out, int out_size, void* d_ws, size_t ws_size,
                              hipStream_t stream)
{
    const float* x0 = (const float*)d_in[0];
    const int*   ei = (const int*)d_in[1];
    const int    N  = in_sizes[0] / 128;   // 100000
    const int    E  = in_sizes[1] / 2;     // 1600000
    const int* src = ei;
    const int* dst = ei + E;

    char* ws = (char*)d_ws;
    size_t off = 0;
    auto carve = [&](size_t bytes) { void* p = ws + off; off += (bytes + 255) & ~(size_t)255; return p; };
    u16*   Wt   = (u16*)carve((size_t)8 * 16384 * sizeof(u16));
    u16*   bufX = (u16*)carve((size_t)N * 128 * sizeof(u16));
    u16*   KS   = (u16*)carve((size_t)N * 256 * sizeof(u16));
    u16*   QV   = (u16*)carve((size_t)N * 256 * sizeof(u16));
    int*   ssrc = (int*)carve((size_t)E * sizeof(int));
    int*   rowp = (int*)carve((size_t)(N + 1) * sizeof(int));
    int*   deg  = (int*)carve((size_t)N * sizeof(int));
    int*   cur  = (int*)carve((size_t)N * sizeof(int));
    float* k3   = (float*)carve((size_t)N * sizeof(float));
    float* q3   = (float*)carve((size_t)N * sizeof(float));
    float* v3   = (float*)carve((size_t)N * sizeof(float));
    float* s3   = (float*)carve((size_t)N * sizeof(float));

    // --- CSR build (once per call) ---
    hipMemsetAsync(deg, 0, (size_t)N * sizeof(int), stream);
    hipMemsetAsync(cur, 0, (size_t)N * sizeof(int), stream);
    hist_k<<<2048, 256, 0, stream>>>(dst, deg, E);
    scan_k<<<1, 1024, 0, stream>>>(deg, rowp, N, E);
    scatter_k<<<2048, 256, 0, stream>>>(src, dst, rowp, cur, ssrc, E);

    // --- weights + x cast ---
    P8 wp;
    wp.p[0] = (const float*)d_in[2];  wp.p[1] = (const float*)d_in[3];
    wp.p[2] = (const float*)d_in[4];  wp.p[3] = (const float*)d_in[5];
    wp.p[4] = (const float*)d_in[7];  wp.p[5] = (const float*)d_in[8];
    wp.p[6] = (const float*)d_in[9];  wp.p[7] = (const float*)d_in[10];
    transpose_w<<<8, 256, 0, stream>>>(wp, Wt);
    cast_f2b<<<1024, 256, 0, stream>>>(x0, bufX, N * 128 / 4);

    int gb = (N + 127) / 128;

    // layer 1
    gemm_kqvs<<<gb, 256, 0, stream>>>(bufX, Wt, (const float*)d_in[6], KS, QV, N);
    edge_csr<<<4096, 256, 0, stream>>>(rowp, ssrc, KS, QV, bufX, N);
    // layer 2
    gemm_kqvs<<<gb, 256, 0, stream>>>(bufX, Wt + 4 * 16384, (const float*)d_in[11], KS, QV, N);
    edge_csr<<<4096, 256, 0, stream>>>(rowp, ssrc, KS, QV, bufX, N);
    // layer 3 (Dout=1)
    gemv3<<<512, 256, 0, stream>>>(bufX,
        (const float*)d_in[12], (const float*)d_in[13], (const float*)d_in[14],
        (const float*)d_in[15], (const float*)d_in[16],
        k3, q3, v3, s3, N);
    edge3_csr<<<1024, 256, 0, stream>>>(rowp, ssrc, k3, q3, v3, s3, (float*)d_out, N);
}

// Round 4
// 785.865 us; speedup vs baseline: 3.8916x; 1.2883x over previous
//
#include <hip/hip_runtime.h>
#include <hip/hip_bf16.h>
#include <cstdint>

typedef unsigned short u16;
typedef unsigned int   u32;
typedef __attribute__((ext_vector_type(8))) short bf16x8;  // 8 bf16 = 4 VGPRs
typedef __attribute__((ext_vector_type(4))) float f32x4;

#define NEG_LOG2E -1.44269504088896f

__device__ __forceinline__ float bf2f(u16 u) {
    union { u32 i; float f; } c; c.i = ((u32)u) << 16; return c.f;
}
__device__ __forceinline__ u16 f2bf(float f) {
    union { float f; u32 i; } c; c.f = f;
    u32 x = c.i;
    return (u16)((x + 0x7fffu + ((x >> 16) & 1u)) >> 16);  // RNE
}
// unpack packed bf16 pair (2 VALU: lshl + and)
__device__ __forceinline__ void bfu2(u32 p, float& lo, float& hi) {
    union { u32 i; float f; } a, b;
    a.i = p << 16; b.i = p & 0xffff0000u;
    lo = a.f; hi = b.f;
}
// gate = sigmoid(k+q) given zt = -log2e*(k+q):  rcp(1 + exp2(zt))
__device__ __forceinline__ float gate(float zt) {
    return __builtin_amdgcn_rcpf(1.0f + __builtin_amdgcn_exp2f(zt));
}

// ---------------------------------------------------------------------------
__global__ void cast_f2b(const float* __restrict__ A, u16* __restrict__ B, int n4) {
    int i  = blockIdx.x * blockDim.x + threadIdx.x;
    int st = gridDim.x * blockDim.x;
    for (; i < n4; i += st) {
        float4 a = ((const float4*)A)[i];
        ushort4 o;
        o.x = f2bf(a.x); o.y = f2bf(a.y); o.z = f2bf(a.z); o.w = f2bf(a.w);
        ((ushort4*)B)[i] = o;
    }
}

// ---------------------------------------------------------------------------
struct P8 { const float* p[8]; };
__global__ void transpose_w(P8 wsrc, u16* __restrict__ Wt) {
    const float* W = wsrc.p[blockIdx.x];
    u16* T = Wt + (size_t)blockIdx.x * 16384;
    int t = threadIdx.x;  // 256 threads
    for (int p = 0; p < 64; ++p) {
        int idx = p * 256 + t;
        int k = idx >> 7, n = idx & 127;
        T[n * 128 + k] = f2bf(W[k * 128 + n]);
    }
}

// ---------------------------------------------------------------------------
// CSR build: histogram -> parallel 3-phase exclusive scan -> scatter
__global__ void hist_k(const int* __restrict__ dst, int* __restrict__ deg, int nE) {
    int i  = blockIdx.x * blockDim.x + threadIdx.x;
    int st = gridDim.x * blockDim.x;
    for (; i < nE; i += st) atomicAdd(&deg[dst[i]], 1);
}

// phase 1: per-block (1024-elem chunk, 256 thr x int4) total
__global__ __launch_bounds__(256)
void scan_part_k(const int* __restrict__ deg, int* __restrict__ part, int N) {
    __shared__ int wsum[4];
    int t = threadIdx.x, lane = t & 63, wave = t >> 6;
    int i0 = blockIdx.x * 1024 + t * 4;
    int s = 0;
    for (int j = 0; j < 4; ++j) { int i = i0 + j; if (i < N) s += deg[i]; }
    for (int off = 32; off > 0; off >>= 1) s += __shfl_xor(s, off);
    if (lane == 0) wsum[wave] = s;
    __syncthreads();
    if (t == 0) part[blockIdx.x] = wsum[0] + wsum[1] + wsum[2] + wsum[3];
}

// phase 2: one block scans the (<=128) block totals -> exclusive offsets
__global__ __launch_bounds__(128)
void scan_tops_k(int* __restrict__ part, int nb) {
    __shared__ int sh[128];
    int t = threadIdx.x;
    int v = (t < nb) ? part[t] : 0;
    sh[t] = v;
    __syncthreads();
    for (int off = 1; off < 128; off <<= 1) {
        int u = (t >= off) ? sh[t - off] : 0;
        __syncthreads();
        sh[t] += u;
        __syncthreads();
    }
    if (t < nb) part[t] = sh[t] - v;  // exclusive
}

// phase 3: re-scan chunk locally, add block offset, emit row_ptr
__global__ __launch_bounds__(256)
void scan_emit_k(const int* __restrict__ deg, const int* __restrict__ part,
                 int* __restrict__ row_ptr, int N, int Etot) {
    __shared__ int woff[4];
    int t = threadIdx.x, lane = t & 63, wave = t >> 6;
    int i0 = blockIdx.x * 1024 + t * 4;
    int d[4]; int s = 0;
    for (int j = 0; j < 4; ++j) { int i = i0 + j; d[j] = (i < N) ? deg[i] : 0; s += d[j]; }
    // inclusive wave scan of s
    int ws = s;
    for (int off = 1; off < 64; off <<= 1) {
        int u = __shfl_up(ws, off);
        if (lane >= off) ws += u;
    }
    if (lane == 63) woff[wave] = ws;
    __syncthreads();
    int base = part[blockIdx.x];
    for (int w = 0; w < wave; ++w) base += woff[w];
    int ex = base + ws - s;  // exclusive prefix for this thread's 4 elems
    for (int j = 0; j < 4; ++j) {
        int i = i0 + j;
        if (i < N) row_ptr[i] = ex;
        ex += d[j];
    }
    if (blockIdx.x == 0 && t == 0) row_ptr[N] = Etot;
}

__global__ void scatter_k(const int* __restrict__ src, const int* __restrict__ dst,
                          const int* __restrict__ row_ptr, int* __restrict__ cur,
                          int* __restrict__ ssrc, int nE) {
    int i  = blockIdx.x * blockDim.x + threadIdx.x;
    int st = gridDim.x * blockDim.x;
    for (; i < nE; i += st) {
        int d = dst[i];
        int pos = row_ptr[d] + atomicAdd(&cur[d], 1);
        ssrc[pos] = src[i];
    }
}

// ---------------------------------------------------------------------------
// Fused GEMM: K~ = -log2e*(x@Wk), Q~ = -log2e*(x@Wq), V = x@Wv, S = x@Ws + b
//   KS[node][0..127]   = K~ row      KS[node][128..255] = S row
//   QV[node][p*4+{0,1}] = Q~[2p..]; QV[node][p*4+{2,3}] = V[2p..]
#define XS 136  // 128 + 8 pad -> 2-way LDS bank aliasing (free per m136)
__global__ __launch_bounds__(256, 2)
void gemm_kqvs(const u16* __restrict__ X, const u16* __restrict__ Wt,
               const float* __restrict__ bias,
               u16* __restrict__ KS, u16* __restrict__ QV, int nrows)
{
    __shared__ u16 xs[128 * XS];
    __shared__ u16 wsl[128 * XS];
    const int tid  = threadIdx.x;
    const int wave = tid >> 6, lane = tid & 63;
    const int quad = lane >> 4, l16 = lane & 15;
    const int r0 = blockIdx.x * 128;

    for (int p = 0; p < 8; ++p) {
        int c = p * 256 + tid;
        int row = c >> 4;
        int col = (c & 15) * 8;
        int gr = r0 + row; if (gr >= nrows) gr = nrows - 1;
        uint4 d = *(const uint4*)(X + (size_t)gr * 128 + col);
        *(uint4*)(&xs[row * XS + col]) = d;
    }

    for (int wi = 0; wi < 4; ++wi) {
        __syncthreads();
        const u16* Wsrc = Wt + wi * (128 * 128);
        for (int p = 0; p < 8; ++p) {
            int c = p * 256 + tid;
            int row = c >> 4;
            int col = (c & 15) * 8;
            uint4 d = *(const uint4*)(Wsrc + row * 128 + col);
            *(uint4*)(&wsl[row * XS + col]) = d;
        }
        __syncthreads();

        f32x4 acc[2][8];
        for (int mt = 0; mt < 2; ++mt)
            for (int nt = 0; nt < 8; ++nt) acc[mt][nt] = (f32x4)0.0f;

        const int rbase = wave * 32;
        for (int kt = 0; kt < 4; ++kt) {
            bf16x8 a0 = *(const bf16x8*)&xs[(rbase + l16)      * XS + kt * 32 + quad * 8];
            bf16x8 a1 = *(const bf16x8*)&xs[(rbase + 16 + l16) * XS + kt * 32 + quad * 8];
            for (int nt = 0; nt < 8; ++nt) {
                bf16x8 b = *(const bf16x8*)&wsl[(nt * 16 + l16) * XS + kt * 32 + quad * 8];
                acc[0][nt] = __builtin_amdgcn_mfma_f32_16x16x32_bf16(a0, b, acc[0][nt], 0, 0, 0);
                acc[1][nt] = __builtin_amdgcn_mfma_f32_16x16x32_bf16(a1, b, acc[1][nt], 0, 0, 0);
            }
        }

        for (int mt = 0; mt < 2; ++mt) {
            int growb = r0 + rbase + mt * 16 + quad * 4;
            for (int r = 0; r < 4; ++r) {
                int grow = growb + r;
                if (grow >= nrows) continue;
                for (int nt = 0; nt < 8; ++nt) {
                    int col = nt * 16 + l16;
                    float vv = acc[mt][nt][r];
                    size_t nb = (size_t)grow * 256;
                    if      (wi == 0) KS[nb + col] = f2bf(NEG_LOG2E * vv);
                    else if (wi == 3) KS[nb + 128 + col] = f2bf(vv + bias[col]);
                    else if (wi == 1) QV[nb + (col >> 1) * 4 + (col & 1)] = f2bf(NEG_LOG2E * vv);
                    else              QV[nb + (col >> 1) * 4 + 2 + (col & 1)] = f2bf(vv);
                }
            }
        }
    }
}

// ---------------------------------------------------------------------------
// CSR gather-reduce edge phase: one wave per dst node.
//   out[d] = relu( S[d] + sum_s rcp(1+exp2(K~[d]+Q~[s])) * V[s] )
// readlane -> SGPR src idx -> scalar-pipe row base; unroll x2, dual accums.
__global__ __launch_bounds__(256)
void edge_csr(const int* __restrict__ row_ptr, const int* __restrict__ ssrc,
              const u16* __restrict__ KS, const u16* __restrict__ QV,
              u16* __restrict__ Xout, int N)
{
    int lane = threadIdx.x & 63;
    int gw = blockIdx.x * (blockDim.x >> 6) + (threadIdx.x >> 6);
    int nw = gridDim.x * (blockDim.x >> 6);
    int c2 = lane * 2;
    for (int d = gw; d < N; d += nw) {
        int beg = row_ptr[d], end = row_ptr[d + 1];
        u32 kk = *(const u32*)(KS + (size_t)d * 256 + c2);
        float k0, k1; bfu2(kk, k0, k1);
        float a0 = 0.0f, a1 = 0.0f, b0 = 0.0f, b1 = 0.0f;
        for (int base = beg; base < end; base += 64) {
            int e = base + lane;
            int s = (e < end) ? ssrc[e] : 0;
            int m = end - base; if (m > 64) m = 64;
            int j = 0;
            for (; j + 2 <= m; j += 2) {
                int s0 = __builtin_amdgcn_readlane(s, j);
                int s1 = __builtin_amdgcn_readlane(s, j + 1);
                uint2 qv0 = *(const uint2*)(QV + (size_t)s0 * 256 + lane * 4);
                uint2 qv1 = *(const uint2*)(QV + (size_t)s1 * 256 + lane * 4);
                float q0, q1, v0, v1;
                bfu2(qv0.x, q0, q1); bfu2(qv0.y, v0, v1);
                a0 += gate(k0 + q0) * v0;
                a1 += gate(k1 + q1) * v1;
                bfu2(qv1.x, q0, q1); bfu2(qv1.y, v0, v1);
                b0 += gate(k0 + q0) * v0;
                b1 += gate(k1 + q1) * v1;
            }
            if (j < m) {
                int s0 = __builtin_amdgcn_readlane(s, j);
                uint2 qv0 = *(const uint2*)(QV + (size_t)s0 * 256 + lane * 4);
                float q0, q1, v0, v1;
                bfu2(qv0.x, q0, q1); bfu2(qv0.y, v0, v1);
                a0 += gate(k0 + q0) * v0;
                a1 += gate(k1 + q1) * v1;
            }
        }
        u32 ss = *(const u32*)(KS + (size_t)d * 256 + 128 + c2);
        float s0f, s1f; bfu2(ss, s0f, s1f);
        float r0 = fmaxf(s0f + a0 + b0, 0.0f);
        float r1 = fmaxf(s1f + a1 + b1, 0.0f);
        *(u32*)(Xout + (size_t)d * 128 + c2) = ((u32)f2bf(r1) << 16) | f2bf(r0);
    }
}

// ---------------------------------------------------------------------------
// Layer 3 (Dout=1): 4 GEMVs, wave per node. k3/q3 stored pre-scaled by -log2e.
__global__ __launch_bounds__(256)
void gemv3(const u16* __restrict__ X,
           const float* __restrict__ Wk, const float* __restrict__ Wq,
           const float* __restrict__ Wv, const float* __restrict__ Ws,
           const float* __restrict__ b3,
           float* __restrict__ k3, float* __restrict__ q3,
           float* __restrict__ v3, float* __restrict__ s3, int N)
{
    int lane = threadIdx.x & 63;
    int gw = blockIdx.x * (blockDim.x >> 6) + (threadIdx.x >> 6);
    int nw = gridDim.x * (blockDim.x >> 6);
    int c2 = lane * 2;
    float2 wk = *(const float2*)(Wk + c2);
    float2 wq = *(const float2*)(Wq + c2);
    float2 wv = *(const float2*)(Wv + c2);
    float2 ws = *(const float2*)(Ws + c2);
    float bias = b3[0];
    for (int i = gw; i < N; i += nw) {
        u32 xx = *(const u32*)(X + (size_t)i * 128 + c2);
        float x0 = bf2f((u16)xx), x1 = bf2f((u16)(xx >> 16));
        float pk = x0 * wk.x + x1 * wk.y;
        float pq = x0 * wq.x + x1 * wq.y;
        float pv = x0 * wv.x + x1 * wv.y;
        float ps = x0 * ws.x + x1 * ws.y;
        for (int off = 32; off > 0; off >>= 1) {
            pk += __shfl_xor(pk, off);
            pq += __shfl_xor(pq, off);
            pv += __shfl_xor(pv, off);
            ps += __shfl_xor(ps, off);
        }
        if (lane == 0) {
            k3[i] = NEG_LOG2E * pk; q3[i] = NEG_LOG2E * pq;
            v3[i] = pv; s3[i] = ps + bias;
        }
    }
}

__global__ __launch_bounds__(256)
void edge3_csr(const int* __restrict__ row_ptr, const int* __restrict__ ssrc,
               const float* __restrict__ k3, const float* __restrict__ q3,
               const float* __restrict__ v3, const float* __restrict__ s3,
               float* __restrict__ outp, int N)
{
    int lane = threadIdx.x & 63;
    int gw = blockIdx.x * (blockDim.x >> 6) + (threadIdx.x >> 6);
    int nw = gridDim.x * (blockDim.x >> 6);
    for (int d = gw; d < N; d += nw) {
        int beg = row_ptr[d], end = row_ptr[d + 1];
        float kd = k3[d];
        float sum = 0.0f;
        for (int e = beg + lane; e < end; e += 64) {
            int s = ssrc[e];
            sum += gate(kd + q3[s]) * v3[s];
        }
        for (int off = 32; off > 0; off >>= 1) sum += __shfl_xor(sum, off);
        if (lane == 0) outp[d] = s3[d] + sum;
    }
}

// ---------------------------------------------------------------------------
extern "C" void kernel_launch(void* const* d_in, const int* in_sizes, int n_in,
                              void* d_out, int out_size, void* d_ws, size_t ws_size,
                              hipStream_t stream)
{
    const float* x0 = (const float*)d_in[0];
    const int*   ei = (const int*)d_in[1];
    const int    N  = in_sizes[0] / 128;   // 100000
    const int    E  = in_sizes[1] / 2;     // 1600000
    const int* src = ei;
    const int* dst = ei + E;

    char* ws = (char*)d_ws;
    size_t off = 0;
    auto carve = [&](size_t bytes) { void* p = ws + off; off += (bytes + 255) & ~(size_t)255; return p; };
    u16*   Wt   = (u16*)carve((size_t)8 * 16384 * sizeof(u16));
    u16*   bufX = (u16*)carve((size_t)N * 128 * sizeof(u16));
    u16*   KS   = (u16*)carve((size_t)N * 256 * sizeof(u16));
    u16*   QV   = (u16*)carve((size_t)N * 256 * sizeof(u16));
    int*   ssrc = (int*)carve((size_t)E * sizeof(int));
    int*   rowp = (int*)carve((size_t)(N + 1) * sizeof(int));
    int*   deg  = (int*)carve((size_t)N * sizeof(int));
    int*   cur  = (int*)carve((size_t)N * sizeof(int));
    int*   part = (int*)carve((size_t)128 * sizeof(int));
    float* k3   = (float*)carve((size_t)N * sizeof(float));
    float* q3   = (float*)carve((size_t)N * sizeof(float));
    float* v3   = (float*)carve((size_t)N * sizeof(float));
    float* s3   = (float*)carve((size_t)N * sizeof(float));

    // --- CSR build ---
    hipMemsetAsync(deg, 0, (size_t)N * sizeof(int), stream);
    hipMemsetAsync(cur, 0, (size_t)N * sizeof(int), stream);
    hist_k<<<2048, 256, 0, stream>>>(dst, deg, E);
    int nb = (N + 1023) / 1024;  // 98
    scan_part_k<<<nb, 256, 0, stream>>>(deg, part, N);
    scan_tops_k<<<1, 128, 0, stream>>>(part, nb);
    scan_emit_k<<<nb, 256, 0, stream>>>(deg, part, rowp, N, E);
    scatter_k<<<2048, 256, 0, stream>>>(src, dst, rowp, cur, ssrc, E);

    // --- weights + x cast ---
    P8 wp;
    wp.p[0] = (const float*)d_in[2];  wp.p[1] = (const float*)d_in[3];
    wp.p[2] = (const float*)d_in[4];  wp.p[3] = (const float*)d_in[5];
    wp.p[4] = (const float*)d_in[7];  wp.p[5] = (const float*)d_in[8];
    wp.p[6] = (const float*)d_in[9];  wp.p[7] = (const float*)d_in[10];
    transpose_w<<<8, 256, 0, stream>>>(wp, Wt);
    cast_f2b<<<1024, 256, 0, stream>>>(x0, bufX, N * 128 / 4);

    int gb = (N + 127) / 128;

    // layer 1
    gemm_kqvs<<<gb, 256, 0, stream>>>(bufX, Wt, (const float*)d_in[6], KS, QV, N);
    edge_csr<<<4096, 256, 0, stream>>>(rowp, ssrc, KS, QV, bufX, N);
    // layer 2
    gemm_kqvs<<<gb, 256, 0, stream>>>(bufX, Wt + 4 * 16384, (const float*)d_in[11], KS, QV, N);
    edge_csr<<<4096, 256, 0, stream>>>(rowp, ssrc, KS, QV, bufX, N);
    // layer 3 (Dout=1)
    gemv3<<<512, 256, 0, stream>>>(bufX,
        (const float*)d_in[12], (const float*)d_in[13], (const float*)d_in[14],
        (const float*)d_in[15], (const float*)d_in[16],
        k3, q3, v3, s3, N);
    edge3_csr<<<1024, 256, 0, stream>>>(rowp, ssrc, k3, q3, v3, s3, (float*)d_out, N);
}

// Round 5
// 705.367 us; speedup vs baseline: 4.3357x; 1.1141x over previous
//
#include <hip/hip_runtime.h>
#include <hip/hip_bf16.h>
#include <cstdint>

typedef unsigned short u16;
typedef unsigned int   u32;
typedef __attribute__((ext_vector_type(8))) short bf16x8;  // 8 bf16 = 4 VGPRs
typedef __attribute__((ext_vector_type(4))) float f32x4;

#define NEG_LOG2E -1.44269504088896f

__device__ __forceinline__ float bf2f(u16 u) {
    union { u32 i; float f; } c; c.i = ((u32)u) << 16; return c.f;
}
__device__ __forceinline__ u16 f2bf(float f) {
    union { float f; u32 i; } c; c.f = f;
    u32 x = c.i;
    return (u16)((x + 0x7fffu + ((x >> 16) & 1u)) >> 16);  // RNE
}
// unpack packed bf16 pair (2 VALU: lshl + and)
__device__ __forceinline__ void bfu2(u32 p, float& lo, float& hi) {
    union { u32 i; float f; } a, b;
    a.i = p << 16; b.i = p & 0xffff0000u;
    lo = a.f; hi = b.f;
}
// gate = sigmoid(k+q) given zt = -log2e*(k+q):  rcp(1 + exp2(zt))
__device__ __forceinline__ float gate(float zt) {
    return __builtin_amdgcn_rcpf(1.0f + __builtin_amdgcn_exp2f(zt));
}

// ---------------------------------------------------------------------------
__global__ void cast_f2b(const float* __restrict__ A, u16* __restrict__ B, int n4) {
    int i  = blockIdx.x * blockDim.x + threadIdx.x;
    int st = gridDim.x * blockDim.x;
    for (; i < n4; i += st) {
        float4 a = ((const float4*)A)[i];
        ushort4 o;
        o.x = f2bf(a.x); o.y = f2bf(a.y); o.z = f2bf(a.z); o.w = f2bf(a.w);
        ((ushort4*)B)[i] = o;
    }
}

// ---------------------------------------------------------------------------
struct P8 { const float* p[8]; };
__global__ void transpose_w(P8 wsrc, u16* __restrict__ Wt) {
    const float* W = wsrc.p[blockIdx.x];
    u16* T = Wt + (size_t)blockIdx.x * 16384;
    int t = threadIdx.x;  // 256 threads
    for (int p = 0; p < 64; ++p) {
        int idx = p * 256 + t;
        int k = idx >> 7, n = idx & 127;
        T[n * 128 + k] = f2bf(W[k * 128 + n]);
    }
}

// ---------------------------------------------------------------------------
// CSR build: histogram -> parallel 3-phase exclusive scan -> scatter
__global__ void hist_k(const int* __restrict__ dst, int* __restrict__ deg, int nE) {
    int i  = blockIdx.x * blockDim.x + threadIdx.x;
    int st = gridDim.x * blockDim.x;
    for (; i < nE; i += st) atomicAdd(&deg[dst[i]], 1);
}

__global__ __launch_bounds__(256)
void scan_part_k(const int* __restrict__ deg, int* __restrict__ part, int N) {
    __shared__ int wsum[4];
    int t = threadIdx.x, lane = t & 63, wave = t >> 6;
    int i0 = blockIdx.x * 1024 + t * 4;
    int s = 0;
    for (int j = 0; j < 4; ++j) { int i = i0 + j; if (i < N) s += deg[i]; }
    for (int off = 32; off > 0; off >>= 1) s += __shfl_xor(s, off);
    if (lane == 0) wsum[wave] = s;
    __syncthreads();
    if (t == 0) part[blockIdx.x] = wsum[0] + wsum[1] + wsum[2] + wsum[3];
}

__global__ __launch_bounds__(128)
void scan_tops_k(int* __restrict__ part, int nb) {
    __shared__ int sh[128];
    int t = threadIdx.x;
    int v = (t < nb) ? part[t] : 0;
    sh[t] = v;
    __syncthreads();
    for (int off = 1; off < 128; off <<= 1) {
        int u = (t >= off) ? sh[t - off] : 0;
        __syncthreads();
        sh[t] += u;
        __syncthreads();
    }
    if (t < nb) part[t] = sh[t] - v;  // exclusive
}

__global__ __launch_bounds__(256)
void scan_emit_k(const int* __restrict__ deg, const int* __restrict__ part,
                 int* __restrict__ row_ptr, int N, int Etot) {
    __shared__ int woff[4];
    int t = threadIdx.x, lane = t & 63, wave = t >> 6;
    int i0 = blockIdx.x * 1024 + t * 4;
    int d[4]; int s = 0;
    for (int j = 0; j < 4; ++j) { int i = i0 + j; d[j] = (i < N) ? deg[i] : 0; s += d[j]; }
    int ws = s;
    for (int off = 1; off < 64; off <<= 1) {
        int u = __shfl_up(ws, off);
        if (lane >= off) ws += u;
    }
    if (lane == 63) woff[wave] = ws;
    __syncthreads();
    int base = part[blockIdx.x];
    for (int w = 0; w < wave; ++w) base += woff[w];
    int ex = base + ws - s;
    for (int j = 0; j < 4; ++j) {
        int i = i0 + j;
        if (i < N) row_ptr[i] = ex;
        ex += d[j];
    }
    if (blockIdx.x == 0 && t == 0) row_ptr[N] = Etot;
}

__global__ void scatter_k(const int* __restrict__ src, const int* __restrict__ dst,
                          const int* __restrict__ row_ptr, int* __restrict__ cur,
                          int* __restrict__ ssrc, int nE) {
    int i  = blockIdx.x * blockDim.x + threadIdx.x;
    int st = gridDim.x * blockDim.x;
    for (; i < nE; i += st) {
        int d = dst[i];
        int pos = row_ptr[d] + atomicAdd(&cur[d], 1);
        ssrc[pos] = src[i];
    }
}

// ---------------------------------------------------------------------------
// Fused GEMM (operand-swapped: A = W^T rows = out-channels, B = X rows = nodes)
//   D[ch][node] -> each lane holds 4 CONSECUTIVE channels of one node
//   KS[node][0..127]   = K~ (canonical)   KS[node][128..255] = S (canonical)
//   QV[node][g*8+0..3] = Q~[4g..4g+3]     QV[node][g*8+4..7] = V[4g..4g+3]
#define XS 136  // 128 + 8 pad -> 2-way LDS bank aliasing (free per m136)
__global__ __launch_bounds__(256, 2)
void gemm_kqvs(const u16* __restrict__ X, const u16* __restrict__ Wt,
               const float* __restrict__ bias,
               u16* __restrict__ KS, u16* __restrict__ QV, int nrows)
{
    __shared__ u16 xs[128 * XS];
    __shared__ u16 wsl[128 * XS];
    const int tid  = threadIdx.x;
    const int wave = tid >> 6, lane = tid & 63;
    const int quad = lane >> 4, l16 = lane & 15;
    const int r0 = blockIdx.x * 128;

    for (int p = 0; p < 8; ++p) {
        int c = p * 256 + tid;
        int row = c >> 4;
        int col = (c & 15) * 8;
        int gr = r0 + row; if (gr >= nrows) gr = nrows - 1;
        uint4 d = *(const uint4*)(X + (size_t)gr * 128 + col);
        *(uint4*)(&xs[row * XS + col]) = d;
    }

    for (int wi = 0; wi < 4; ++wi) {
        __syncthreads();
        const u16* Wsrc = Wt + wi * (128 * 128);
        for (int p = 0; p < 8; ++p) {
            int c = p * 256 + tid;
            int row = c >> 4;
            int col = (c & 15) * 8;
            uint4 d = *(const uint4*)(Wsrc + row * 128 + col);
            *(uint4*)(&wsl[row * XS + col]) = d;
        }
        __syncthreads();

        f32x4 acc[2][8];
        for (int mt = 0; mt < 2; ++mt)
            for (int nt = 0; nt < 8; ++nt) acc[mt][nt] = (f32x4)0.0f;

        const int cbase = wave * 32;  // this wave's 32 output channels
        for (int kt = 0; kt < 4; ++kt) {
            // A = weights: A[m=ch=l16][k=quad*8+j]
            bf16x8 a0 = *(const bf16x8*)&wsl[(cbase + l16)      * XS + kt * 32 + quad * 8];
            bf16x8 a1 = *(const bf16x8*)&wsl[(cbase + 16 + l16) * XS + kt * 32 + quad * 8];
            for (int nt = 0; nt < 8; ++nt) {
                // B = X^T: B[k=quad*8+j][n=node=l16] read from xs node-rows
                bf16x8 b = *(const bf16x8*)&xs[(nt * 16 + l16) * XS + kt * 32 + quad * 8];
                acc[0][nt] = __builtin_amdgcn_mfma_f32_16x16x32_bf16(a0, b, acc[0][nt], 0, 0, 0);
                acc[1][nt] = __builtin_amdgcn_mfma_f32_16x16x32_bf16(a1, b, acc[1][nt], 0, 0, 0);
            }
        }

        // epilogue: lane holds channels chb..chb+3 of node (nt*16+l16)
        float4 bias4[2];
        if (wi == 3) {
            bias4[0] = *(const float4*)(bias + cbase + quad * 4);
            bias4[1] = *(const float4*)(bias + cbase + 16 + quad * 4);
        }
        for (int mt = 0; mt < 2; ++mt) {
            int chb = cbase + mt * 16 + quad * 4;
            for (int nt = 0; nt < 8; ++nt) {
                int node = r0 + nt * 16 + l16;
                if (node >= nrows) continue;
                f32x4 v = acc[mt][nt];
                float x0 = v[0], x1 = v[1], x2 = v[2], x3 = v[3];
                if (wi == 0 || wi == 1) {
                    x0 *= NEG_LOG2E; x1 *= NEG_LOG2E; x2 *= NEG_LOG2E; x3 *= NEG_LOG2E;
                } else if (wi == 3) {
                    x0 += bias4[mt].x; x1 += bias4[mt].y;
                    x2 += bias4[mt].z; x3 += bias4[mt].w;
                }
                uint2 st;
                st.x = ((u32)f2bf(x1) << 16) | f2bf(x0);
                st.y = ((u32)f2bf(x3) << 16) | f2bf(x2);
                size_t nb = (size_t)node * 256;
                if      (wi == 0) *(uint2*)(KS + nb + chb) = st;
                else if (wi == 3) *(uint2*)(KS + nb + 128 + chb) = st;
                else if (wi == 1) *(uint2*)(QV + nb + 2 * chb) = st;
                else              *(uint2*)(QV + nb + 2 * chb + 4) = st;
            }
        }
    }
}

// ---------------------------------------------------------------------------
// CSR gather-reduce edge phase: one wave per dst node, TWO edges per iteration
// (half-wave per edge, lane covers 4 channels via one dwordx4 row load).
// MODE 0: write relu row to Xout (bf16). MODE 1: fuse layer-3 GEMV, write
// k3/qv3/s3 per node instead.
template<int MODE>
__global__ __launch_bounds__(256)
void edge_csr2(const int* __restrict__ rowp, const int* __restrict__ ssrc,
               const u16* __restrict__ KS, const u16* __restrict__ QV,
               u16* __restrict__ Xout,
               const float* __restrict__ Wk3, const float* __restrict__ Wq3,
               const float* __restrict__ Wv3, const float* __restrict__ Ws3,
               const float* __restrict__ b3,
               float* __restrict__ k3, float2* __restrict__ qv3,
               float* __restrict__ s3, int N)
{
    const int lane = threadIdx.x & 63;
    const int half = lane >> 5;
    const int t    = lane & 31;       // channel group: channels 4t..4t+3
    int gw = blockIdx.x * (blockDim.x >> 6) + (threadIdx.x >> 6);
    int nw = gridDim.x * (blockDim.x >> 6);

    float4 wk4, wq4, wv4, ws4;
    float bias3 = 0.0f;
    if (MODE == 1) {
        wk4 = *(const float4*)(Wk3 + 4 * t);
        wq4 = *(const float4*)(Wq3 + 4 * t);
        wv4 = *(const float4*)(Wv3 + 4 * t);
        ws4 = *(const float4*)(Ws3 + 4 * t);
        bias3 = b3[0];
    }

    for (int d = gw; d < N; d += nw) {
        int beg = rowp[d], end = rowp[d + 1];
        uint2 kk = *(const uint2*)(KS + (size_t)d * 256 + t * 4);
        float k0, k1, k2, k3v;
        bfu2(kk.x, k0, k1); bfu2(kk.y, k2, k3v);
        float a0 = 0.f, a1 = 0.f, a2 = 0.f, a3 = 0.f;
        float e0 = 0.f, e1 = 0.f, e2 = 0.f, e3 = 0.f;

#define EDGE_STEP(S0, S1, A0, A1, A2, A3)                                         \
        {                                                                         \
            const uint4* p_ = (const uint4*)(QV + (size_t)(half ? (S1) : (S0)) * 256) + t; \
            uint4 qv_ = *p_;                                                      \
            float q0_, q1_, q2_, q3_, v0_, v1_, v2_, v3_;                         \
            bfu2(qv_.x, q0_, q1_); bfu2(qv_.y, q2_, q3_);                         \
            bfu2(qv_.z, v0_, v1_); bfu2(qv_.w, v2_, v3_);                         \
            A0 += gate(k0 + q0_) * v0_;  A1 += gate(k1 + q1_) * v1_;              \
            A2 += gate(k2 + q2_) * v2_;  A3 += gate(k3v + q3_) * v3_;             \
        }

        for (int base = beg; base < end; base += 64) {
            int e = base + lane;
            int sv = (e < end) ? ssrc[e] : 0;
            int m = end - base; if (m > 64) m = 64;
            int j = 0;
            for (; j + 4 <= m; j += 4) {
                int sA0 = __builtin_amdgcn_readlane(sv, j);
                int sA1 = __builtin_amdgcn_readlane(sv, j + 1);
                int sB0 = __builtin_amdgcn_readlane(sv, j + 2);
                int sB1 = __builtin_amdgcn_readlane(sv, j + 3);
                EDGE_STEP(sA0, sA1, a0, a1, a2, a3);
                EDGE_STEP(sB0, sB1, e0, e1, e2, e3);
            }
            if (j + 2 <= m) {
                int sA0 = __builtin_amdgcn_readlane(sv, j);
                int sA1 = __builtin_amdgcn_readlane(sv, j + 1);
                EDGE_STEP(sA0, sA1, a0, a1, a2, a3);
                j += 2;
            }
            if (j < m) {  // single odd edge: only half 0 accumulates
                int s0i = __builtin_amdgcn_readlane(sv, j);
                const uint4* p_ = (const uint4*)(QV + (size_t)s0i * 256) + t;
                uint4 qv_ = *p_;
                float q0_, q1_, q2_, q3_, v0_, v1_, v2_, v3_;
                bfu2(qv_.x, q0_, q1_); bfu2(qv_.y, q2_, q3_);
                bfu2(qv_.z, v0_, v1_); bfu2(qv_.w, v2_, v3_);
                if (half == 0) {
                    a0 += gate(k0 + q0_) * v0_;  a1 += gate(k1 + q1_) * v1_;
                    a2 += gate(k2 + q2_) * v2_;  a3 += gate(k3v + q3_) * v3_;
                }
            }
        }
#undef EDGE_STEP

        a0 += e0; a1 += e1; a2 += e2; a3 += e3;
        a0 += __shfl_xor(a0, 32);
        a1 += __shfl_xor(a1, 32);
        a2 += __shfl_xor(a2, 32);
        a3 += __shfl_xor(a3, 32);

        uint2 ss = *(const uint2*)(KS + (size_t)d * 256 + 128 + t * 4);
        float s0f, s1f, s2f, s3f;
        bfu2(ss.x, s0f, s1f); bfu2(ss.y, s2f, s3f);
        float r0 = fmaxf(s0f + a0, 0.f);
        float r1 = fmaxf(s1f + a1, 0.f);
        float r2 = fmaxf(s2f + a2, 0.f);
        float r3 = fmaxf(s3f + a3, 0.f);

        if (MODE == 0) {
            if (half == 0) {
                uint2 st;
                st.x = ((u32)f2bf(r1) << 16) | f2bf(r0);
                st.y = ((u32)f2bf(r3) << 16) | f2bf(r2);
                *(uint2*)(Xout + (size_t)d * 128 + t * 4) = st;
            }
        } else {
            float pk = r0 * wk4.x + r1 * wk4.y + r2 * wk4.z + r3 * wk4.w;
            float pq = r0 * wq4.x + r1 * wq4.y + r2 * wq4.z + r3 * wq4.w;
            float pv = r0 * wv4.x + r1 * wv4.y + r2 * wv4.z + r3 * wv4.w;
            float ps = r0 * ws4.x + r1 * ws4.y + r2 * ws4.z + r3 * ws4.w;
            for (int off = 1; off < 32; off <<= 1) {
                pk += __shfl_xor(pk, off);
                pq += __shfl_xor(pq, off);
                pv += __shfl_xor(pv, off);
                ps += __shfl_xor(ps, off);
            }
            if (lane == 0) {
                k3[d]  = NEG_LOG2E * pk;
                qv3[d] = make_float2(NEG_LOG2E * pq, pv);
                s3[d]  = ps + bias3;
            }
        }
    }
}

// ---------------------------------------------------------------------------
// CSR edge phase, Dout=1: wave per node; qv3 packed float2 (one 8B gather).
__global__ __launch_bounds__(256)
void edge3_csr(const int* __restrict__ rowp, const int* __restrict__ ssrc,
               const float* __restrict__ k3, const float2* __restrict__ qv3,
               const float* __restrict__ s3, float* __restrict__ outp, int N)
{
    int lane = threadIdx.x & 63;
    int gw = blockIdx.x * (blockDim.x >> 6) + (threadIdx.x >> 6);
    int nw = gridDim.x * (blockDim.x >> 6);
    for (int d = gw; d < N; d += nw) {
        int beg = rowp[d], end = rowp[d + 1];
        float kd = k3[d];
        float sum = 0.0f;
        for (int e = beg + lane; e < end; e += 64) {
            float2 qv = qv3[ssrc[e]];
            sum += gate(kd + qv.x) * qv.y;
        }
        for (int off = 32; off > 0; off >>= 1) sum += __shfl_xor(sum, off);
        if (lane == 0) outp[d] = s3[d] + sum;
    }
}

// ---------------------------------------------------------------------------
extern "C" void kernel_launch(void* const* d_in, const int* in_sizes, int n_in,
                              void* d_out, int out_size, void* d_ws, size_t ws_size,
                              hipStream_t stream)
{
    const float* x0 = (const float*)d_in[0];
    const int*   ei = (const int*)d_in[1];
    const int    N  = in_sizes[0] / 128;   // 100000
    const int    E  = in_sizes[1] / 2;     // 1600000
    const int* src = ei;
    const int* dst = ei + E;

    char* ws = (char*)d_ws;
    size_t off = 0;
    auto carve = [&](size_t bytes) { void* p = ws + off; off += (bytes + 255) & ~(size_t)255; return p; };
    u16*    Wt   = (u16*)carve((size_t)8 * 16384 * sizeof(u16));
    u16*    bufX = (u16*)carve((size_t)N * 128 * sizeof(u16));
    u16*    KS   = (u16*)carve((size_t)N * 256 * sizeof(u16));
    u16*    QV   = (u16*)carve((size_t)N * 256 * sizeof(u16));
    int*    ssrc = (int*)carve((size_t)E * sizeof(int));
    int*    rowp = (int*)carve((size_t)(N + 1) * sizeof(int));
    int*    deg  = (int*)carve((size_t)N * sizeof(int));
    int*    cur  = (int*)carve((size_t)N * sizeof(int));
    int*    part = (int*)carve((size_t)128 * sizeof(int));
    float*  k3   = (float*)carve((size_t)N * sizeof(float));
    float2* qv3  = (float2*)carve((size_t)N * sizeof(float2));
    float*  s3   = (float*)carve((size_t)N * sizeof(float));

    // --- CSR build ---
    hipMemsetAsync(deg, 0, (size_t)N * sizeof(int), stream);
    hipMemsetAsync(cur, 0, (size_t)N * sizeof(int), stream);
    hist_k<<<2048, 256, 0, stream>>>(dst, deg, E);
    int nb = (N + 1023) / 1024;  // 98
    scan_part_k<<<nb, 256, 0, stream>>>(deg, part, N);
    scan_tops_k<<<1, 128, 0, stream>>>(part, nb);
    scan_emit_k<<<nb, 256, 0, stream>>>(deg, part, rowp, N, E);
    scatter_k<<<2048, 256, 0, stream>>>(src, dst, rowp, cur, ssrc, E);

    // --- weights + x cast ---
    P8 wp;
    wp.p[0] = (const float*)d_in[2];  wp.p[1] = (const float*)d_in[3];
    wp.p[2] = (const float*)d_in[4];  wp.p[3] = (const float*)d_in[5];
    wp.p[4] = (const float*)d_in[7];  wp.p[5] = (const float*)d_in[8];
    wp.p[6] = (const float*)d_in[9];  wp.p[7] = (const float*)d_in[10];
    transpose_w<<<8, 256, 0, stream>>>(wp, Wt);
    cast_f2b<<<1024, 256, 0, stream>>>(x0, bufX, N * 128 / 4);

    int gb = (N + 127) / 128;

    // layer 1
    gemm_kqvs<<<gb, 256, 0, stream>>>(bufX, Wt, (const float*)d_in[6], KS, QV, N);
    edge_csr2<0><<<4096, 256, 0, stream>>>(rowp, ssrc, KS, QV, bufX,
        nullptr, nullptr, nullptr, nullptr, nullptr, nullptr, nullptr, nullptr, N);
    // layer 2 (+ fused layer-3 GEMV)
    gemm_kqvs<<<gb, 256, 0, stream>>>(bufX, Wt + 4 * 16384, (const float*)d_in[11], KS, QV, N);
    edge_csr2<1><<<4096, 256, 0, stream>>>(rowp, ssrc, KS, QV, nullptr,
        (const float*)d_in[12], (const float*)d_in[13], (const float*)d_in[14],
        (const float*)d_in[15], (const float*)d_in[16],
        k3, qv3, s3, N);
    // layer 3 edge pass -> d_out
    edge3_csr<<<1024, 256, 0, stream>>>(rowp, ssrc, k3, qv3, s3, (float*)d_out, N);
}

// Round 6
// 688.194 us; speedup vs baseline: 4.4439x; 1.0250x over previous
//
#include <hip/hip_runtime.h>
#include <hip/hip_bf16.h>
#include <cstdint>

typedef unsigned short u16;
typedef unsigned int   u32;
typedef __attribute__((ext_vector_type(8))) short bf16x8;  // 8 bf16 = 4 VGPRs
typedef __attribute__((ext_vector_type(4))) float f32x4;

#define NEG_LOG2E -1.44269504088896f

__device__ __forceinline__ float bf2f(u16 u) {
    union { u32 i; float f; } c; c.i = ((u32)u) << 16; return c.f;
}
__device__ __forceinline__ u16 f2bf(float f) {
    union { float f; u32 i; } c; c.f = f;
    u32 x = c.i;
    return (u16)((x + 0x7fffu + ((x >> 16) & 1u)) >> 16);  // RNE
}
// unpack packed bf16 pair (2 VALU: lshl + and)
__device__ __forceinline__ void bfu2(u32 p, float& lo, float& hi) {
    union { u32 i; float f; } a, b;
    a.i = p << 16; b.i = p & 0xffff0000u;
    lo = a.f; hi = b.f;
}
// gate = sigmoid(k+q) given zt = -log2e*(k+q):  rcp(1 + exp2(zt))
__device__ __forceinline__ float gate(float zt) {
    return __builtin_amdgcn_rcpf(1.0f + __builtin_amdgcn_exp2f(zt));
}

// ---------------------------------------------------------------------------
__global__ void cast_f2b(const float* __restrict__ A, u16* __restrict__ B, int n4) {
    int i  = blockIdx.x * blockDim.x + threadIdx.x;
    int st = gridDim.x * blockDim.x;
    for (; i < n4; i += st) {
        float4 a = ((const float4*)A)[i];
        ushort4 o;
        o.x = f2bf(a.x); o.y = f2bf(a.y); o.z = f2bf(a.z); o.w = f2bf(a.w);
        ((ushort4*)B)[i] = o;
    }
}

// ---------------------------------------------------------------------------
struct P8 { const float* p[8]; };
__global__ void transpose_w(P8 wsrc, u16* __restrict__ Wt) {
    const float* W = wsrc.p[blockIdx.x];
    u16* T = Wt + (size_t)blockIdx.x * 16384;
    int t = threadIdx.x;  // 256 threads
    for (int p = 0; p < 64; ++p) {
        int idx = p * 256 + t;
        int k = idx >> 7, n = idx & 127;
        T[n * 128 + k] = f2bf(W[k * 128 + n]);
    }
}

// ---------------------------------------------------------------------------
// CSR build: histogram -> parallel 3-phase exclusive scan -> scatter
__global__ void hist_k(const int* __restrict__ dst, int* __restrict__ deg, int nE) {
    int i  = blockIdx.x * blockDim.x + threadIdx.x;
    int st = gridDim.x * blockDim.x;
    for (; i < nE; i += st) atomicAdd(&deg[dst[i]], 1);
}

__global__ __launch_bounds__(256)
void scan_part_k(const int* __restrict__ deg, int* __restrict__ part, int N) {
    __shared__ int wsum[4];
    int t = threadIdx.x, lane = t & 63, wave = t >> 6;
    int i0 = blockIdx.x * 1024 + t * 4;
    int s = 0;
    for (int j = 0; j < 4; ++j) { int i = i0 + j; if (i < N) s += deg[i]; }
    for (int off = 32; off > 0; off >>= 1) s += __shfl_xor(s, off);
    if (lane == 0) wsum[wave] = s;
    __syncthreads();
    if (t == 0) part[blockIdx.x] = wsum[0] + wsum[1] + wsum[2] + wsum[3];
}

__global__ __launch_bounds__(128)
void scan_tops_k(int* __restrict__ part, int nb) {
    __shared__ int sh[128];
    int t = threadIdx.x;
    int v = (t < nb) ? part[t] : 0;
    sh[t] = v;
    __syncthreads();
    for (int off = 1; off < 128; off <<= 1) {
        int u = (t >= off) ? sh[t - off] : 0;
        __syncthreads();
        sh[t] += u;
        __syncthreads();
    }
    if (t < nb) part[t] = sh[t] - v;  // exclusive
}

__global__ __launch_bounds__(256)
void scan_emit_k(const int* __restrict__ deg, const int* __restrict__ part,
                 int* __restrict__ row_ptr, int N, int Etot) {
    __shared__ int woff[4];
    int t = threadIdx.x, lane = t & 63, wave = t >> 6;
    int i0 = blockIdx.x * 1024 + t * 4;
    int d[4]; int s = 0;
    for (int j = 0; j < 4; ++j) { int i = i0 + j; d[j] = (i < N) ? deg[i] : 0; s += d[j]; }
    int ws = s;
    for (int off = 1; off < 64; off <<= 1) {
        int u = __shfl_up(ws, off);
        if (lane >= off) ws += u;
    }
    if (lane == 63) woff[wave] = ws;
    __syncthreads();
    int base = part[blockIdx.x];
    for (int w = 0; w < wave; ++w) base += woff[w];
    int ex = base + ws - s;
    for (int j = 0; j < 4; ++j) {
        int i = i0 + j;
        if (i < N) row_ptr[i] = ex;
        ex += d[j];
    }
    if (blockIdx.x == 0 && t == 0) row_ptr[N] = Etot;
}

__global__ void scatter_k(const int* __restrict__ src, const int* __restrict__ dst,
                          const int* __restrict__ row_ptr, int* __restrict__ cur,
                          int* __restrict__ ssrc, int nE) {
    int i  = blockIdx.x * blockDim.x + threadIdx.x;
    int st = gridDim.x * blockDim.x;
    for (; i < nE; i += st) {
        int d = dst[i];
        int pos = row_ptr[d] + atomicAdd(&cur[d], 1);
        ssrc[pos] = src[i];
    }
}

// ---------------------------------------------------------------------------
// Fused GEMM (operand-swapped: A = W^T rows = out-channels, B = X rows = nodes)
//   D[ch][node] -> each lane holds 4 CONSECUTIVE channels of one node
//   KS[node][0..127]   = K~ (canonical)   KS[node][128..255] = S (canonical)
//   QV[node][g*8+0..3] = Q~[4g..4g+3]     QV[node][g*8+4..7] = V[4g..4g+3]
#define XS 136  // 128 + 8 pad -> 2-way LDS bank aliasing (free per m136)
__global__ __launch_bounds__(256, 2)
void gemm_kqvs(const u16* __restrict__ X, const u16* __restrict__ Wt,
               const float* __restrict__ bias,
               u16* __restrict__ KS, u16* __restrict__ QV, int nrows)
{
    __shared__ u16 xs[128 * XS];
    __shared__ u16 wsl[128 * XS];
    const int tid  = threadIdx.x;
    const int wave = tid >> 6, lane = tid & 63;
    const int quad = lane >> 4, l16 = lane & 15;
    const int r0 = blockIdx.x * 128;

    for (int p = 0; p < 8; ++p) {
        int c = p * 256 + tid;
        int row = c >> 4;
        int col = (c & 15) * 8;
        int gr = r0 + row; if (gr >= nrows) gr = nrows - 1;
        uint4 d = *(const uint4*)(X + (size_t)gr * 128 + col);
        *(uint4*)(&xs[row * XS + col]) = d;
    }

    for (int wi = 0; wi < 4; ++wi) {
        __syncthreads();
        const u16* Wsrc = Wt + wi * (128 * 128);
        for (int p = 0; p < 8; ++p) {
            int c = p * 256 + tid;
            int row = c >> 4;
            int col = (c & 15) * 8;
            uint4 d = *(const uint4*)(Wsrc + row * 128 + col);
            *(uint4*)(&wsl[row * XS + col]) = d;
        }
        __syncthreads();

        f32x4 acc[2][8];
        for (int mt = 0; mt < 2; ++mt)
            for (int nt = 0; nt < 8; ++nt) acc[mt][nt] = (f32x4)0.0f;

        const int cbase = wave * 32;  // this wave's 32 output channels
        for (int kt = 0; kt < 4; ++kt) {
            bf16x8 a0 = *(const bf16x8*)&wsl[(cbase + l16)      * XS + kt * 32 + quad * 8];
            bf16x8 a1 = *(const bf16x8*)&wsl[(cbase + 16 + l16) * XS + kt * 32 + quad * 8];
            for (int nt = 0; nt < 8; ++nt) {
                bf16x8 b = *(const bf16x8*)&xs[(nt * 16 + l16) * XS + kt * 32 + quad * 8];
                acc[0][nt] = __builtin_amdgcn_mfma_f32_16x16x32_bf16(a0, b, acc[0][nt], 0, 0, 0);
                acc[1][nt] = __builtin_amdgcn_mfma_f32_16x16x32_bf16(a1, b, acc[1][nt], 0, 0, 0);
            }
        }

        float4 bias4[2];
        if (wi == 3) {
            bias4[0] = *(const float4*)(bias + cbase + quad * 4);
            bias4[1] = *(const float4*)(bias + cbase + 16 + quad * 4);
        }
        for (int mt = 0; mt < 2; ++mt) {
            int chb = cbase + mt * 16 + quad * 4;
            for (int nt = 0; nt < 8; ++nt) {
                int node = r0 + nt * 16 + l16;
                if (node >= nrows) continue;
                f32x4 v = acc[mt][nt];
                float x0 = v[0], x1 = v[1], x2 = v[2], x3 = v[3];
                if (wi == 0 || wi == 1) {
                    x0 *= NEG_LOG2E; x1 *= NEG_LOG2E; x2 *= NEG_LOG2E; x3 *= NEG_LOG2E;
                } else if (wi == 3) {
                    x0 += bias4[mt].x; x1 += bias4[mt].y;
                    x2 += bias4[mt].z; x3 += bias4[mt].w;
                }
                uint2 st;
                st.x = ((u32)f2bf(x1) << 16) | f2bf(x0);
                st.y = ((u32)f2bf(x3) << 16) | f2bf(x2);
                size_t nb = (size_t)node * 256;
                if      (wi == 0) *(uint2*)(KS + nb + chb) = st;
                else if (wi == 3) *(uint2*)(KS + nb + 128 + chb) = st;
                else if (wi == 1) *(uint2*)(QV + nb + 2 * chb) = st;
                else              *(uint2*)(QV + nb + 2 * chb + 4) = st;
            }
        }
    }
}

// ---------------------------------------------------------------------------
// CSR gather-reduce edge phase: one wave per dst node, TWO edges per load
// (half-wave per edge, lane covers 4 channels via one dwordx4 row load).
// 8-edge unroll -> 4 independent loads in flight (MLP=4).
// MODE 0: write relu row to Xout (bf16). MODE 1: fuse layer-3 GEMV.
template<int MODE>
__global__ __launch_bounds__(256)
void edge_csr2(const int* __restrict__ rowp, const int* __restrict__ ssrc,
               const u16* __restrict__ KS, const u16* __restrict__ QV,
               u16* __restrict__ Xout,
               const float* __restrict__ Wk3, const float* __restrict__ Wq3,
               const float* __restrict__ Wv3, const float* __restrict__ Ws3,
               const float* __restrict__ b3,
               float* __restrict__ k3, float2* __restrict__ qv3,
               float* __restrict__ s3, int N)
{
    const int lane = threadIdx.x & 63;
    const int half = lane >> 5;
    const int t    = lane & 31;       // channel group: channels 4t..4t+3
    int gw = blockIdx.x * (blockDim.x >> 6) + (threadIdx.x >> 6);
    int nw = gridDim.x * (blockDim.x >> 6);

    float4 wk4, wq4, wv4, ws4;
    float bias3 = 0.0f;
    if (MODE == 1) {
        wk4 = *(const float4*)(Wk3 + 4 * t);
        wq4 = *(const float4*)(Wq3 + 4 * t);
        wv4 = *(const float4*)(Wv3 + 4 * t);
        ws4 = *(const float4*)(Ws3 + 4 * t);
        bias3 = b3[0];
    }

#define LOAD2(S0, S1) (*((const uint4*)(QV + (size_t)(half ? (S1) : (S0)) * 256) + t))
#define COMP(QVv, A0, A1, A2, A3)                                             \
    {                                                                         \
        float q0_, q1_, q2_, q3_, v0_, v1_, v2_, v3_;                         \
        bfu2((QVv).x, q0_, q1_); bfu2((QVv).y, q2_, q3_);                     \
        bfu2((QVv).z, v0_, v1_); bfu2((QVv).w, v2_, v3_);                     \
        A0 += gate(k0 + q0_) * v0_;  A1 += gate(k1 + q1_) * v1_;              \
        A2 += gate(k2 + q2_) * v2_;  A3 += gate(k3v + q3_) * v3_;             \
    }

    for (int d = gw; d < N; d += nw) {
        int beg = rowp[d], end = rowp[d + 1];
        uint2 kk = *(const uint2*)(KS + (size_t)d * 256 + t * 4);
        float k0, k1, k2, k3v;
        bfu2(kk.x, k0, k1); bfu2(kk.y, k2, k3v);
        float a0 = 0.f, a1 = 0.f, a2 = 0.f, a3 = 0.f;
        float e0 = 0.f, e1 = 0.f, e2 = 0.f, e3 = 0.f;

        for (int base = beg; base < end; base += 64) {
            int e = base + lane;
            int sv = (e < end) ? ssrc[e] : 0;
            int m = end - base; if (m > 64) m = 64;
            int j = 0;
            for (; j + 8 <= m; j += 8) {
                int sa0 = __builtin_amdgcn_readlane(sv, j);
                int sa1 = __builtin_amdgcn_readlane(sv, j + 1);
                int sb0 = __builtin_amdgcn_readlane(sv, j + 2);
                int sb1 = __builtin_amdgcn_readlane(sv, j + 3);
                int sc0 = __builtin_amdgcn_readlane(sv, j + 4);
                int sc1 = __builtin_amdgcn_readlane(sv, j + 5);
                int sd0 = __builtin_amdgcn_readlane(sv, j + 6);
                int sd1 = __builtin_amdgcn_readlane(sv, j + 7);
                uint4 qA = LOAD2(sa0, sa1);
                uint4 qB = LOAD2(sb0, sb1);
                uint4 qC = LOAD2(sc0, sc1);
                uint4 qD = LOAD2(sd0, sd1);
                COMP(qA, a0, a1, a2, a3);
                COMP(qB, e0, e1, e2, e3);
                COMP(qC, a0, a1, a2, a3);
                COMP(qD, e0, e1, e2, e3);
            }
            for (; j + 2 <= m; j += 2) {
                int s0 = __builtin_amdgcn_readlane(sv, j);
                int s1 = __builtin_amdgcn_readlane(sv, j + 1);
                uint4 qA = LOAD2(s0, s1);
                COMP(qA, a0, a1, a2, a3);
            }
            if (j < m) {  // single odd edge: only half 0 accumulates
                int s0i = __builtin_amdgcn_readlane(sv, j);
                uint4 qv_ = *((const uint4*)(QV + (size_t)s0i * 256) + t);
                float q0_, q1_, q2_, q3_, v0_, v1_, v2_, v3_;
                bfu2(qv_.x, q0_, q1_); bfu2(qv_.y, q2_, q3_);
                bfu2(qv_.z, v0_, v1_); bfu2(qv_.w, v2_, v3_);
                if (half == 0) {
                    a0 += gate(k0 + q0_) * v0_;  a1 += gate(k1 + q1_) * v1_;
                    a2 += gate(k2 + q2_) * v2_;  a3 += gate(k3v + q3_) * v3_;
                }
            }
        }
#undef LOAD2
#undef COMP

        a0 += e0; a1 += e1; a2 += e2; a3 += e3;
        a0 += __shfl_xor(a0, 32);
        a1 += __shfl_xor(a1, 32);
        a2 += __shfl_xor(a2, 32);
        a3 += __shfl_xor(a3, 32);

        uint2 ss = *(const uint2*)(KS + (size_t)d * 256 + 128 + t * 4);
        float s0f, s1f, s2f, s3f;
        bfu2(ss.x, s0f, s1f); bfu2(ss.y, s2f, s3f);
        float r0 = fmaxf(s0f + a0, 0.f);
        float r1 = fmaxf(s1f + a1, 0.f);
        float r2 = fmaxf(s2f + a2, 0.f);
        float r3 = fmaxf(s3f + a3, 0.f);

        if (MODE == 0) {
            if (half == 0) {
                uint2 st;
                st.x = ((u32)f2bf(r1) << 16) | f2bf(r0);
                st.y = ((u32)f2bf(r3) << 16) | f2bf(r2);
                *(uint2*)(Xout + (size_t)d * 128 + t * 4) = st;
            }
        } else {
            float pk = r0 * wk4.x + r1 * wk4.y + r2 * wk4.z + r3 * wk4.w;
            float pq = r0 * wq4.x + r1 * wq4.y + r2 * wq4.z + r3 * wq4.w;
            float pv = r0 * wv4.x + r1 * wv4.y + r2 * wv4.z + r3 * wv4.w;
            float ps = r0 * ws4.x + r1 * ws4.y + r2 * ws4.z + r3 * ws4.w;
            for (int off = 1; off < 32; off <<= 1) {
                pk += __shfl_xor(pk, off);
                pq += __shfl_xor(pq, off);
                pv += __shfl_xor(pv, off);
                ps += __shfl_xor(ps, off);
            }
            if (lane == 0) {
                k3[d]  = NEG_LOG2E * pk;
                qv3[d] = make_float2(NEG_LOG2E * pq, pv);
                s3[d]  = ps + bias3;
            }
        }
    }
}

// ---------------------------------------------------------------------------
// CSR edge phase, Dout=1: wave per node; qv3 packed float2 (one 8B gather).
__global__ __launch_bounds__(256)
void edge3_csr(const int* __restrict__ rowp, const int* __restrict__ ssrc,
               const float* __restrict__ k3, const float2* __restrict__ qv3,
               const float* __restrict__ s3, float* __restrict__ outp, int N)
{
    int lane = threadIdx.x & 63;
    int gw = blockIdx.x * (blockDim.x >> 6) + (threadIdx.x >> 6);
    int nw = gridDim.x * (blockDim.x >> 6);
    for (int d = gw; d < N; d += nw) {
        int beg = rowp[d], end = rowp[d + 1];
        float kd = k3[d];
        float sum = 0.0f;
        for (int e = beg + lane; e < end; e += 64) {
            float2 qv = qv3[ssrc[e]];
            sum += gate(kd + qv.x) * qv.y;
        }
        for (int off = 32; off > 0; off >>= 1) sum += __shfl_xor(sum, off);
        if (lane == 0) outp[d] = s3[d] + sum;
    }
}

// ---------------------------------------------------------------------------
extern "C" void kernel_launch(void* const* d_in, const int* in_sizes, int n_in,
                              void* d_out, int out_size, void* d_ws, size_t ws_size,
                              hipStream_t stream)
{
    const float* x0 = (const float*)d_in[0];
    const int*   ei = (const int*)d_in[1];
    const int    N  = in_sizes[0] / 128;   // 100000
    const int    E  = in_sizes[1] / 2;     // 1600000
    const int* src = ei;
    const int* dst = ei + E;

    char* ws = (char*)d_ws;
    size_t off = 0;
    auto carve = [&](size_t bytes) { void* p = ws + off; off += (bytes + 255) & ~(size_t)255; return p; };
    u16*    Wt   = (u16*)carve((size_t)8 * 16384 * sizeof(u16));
    u16*    bufX = (u16*)carve((size_t)N * 128 * sizeof(u16));
    u16*    KS   = (u16*)carve((size_t)N * 256 * sizeof(u16));
    u16*    QV   = (u16*)carve((size_t)N * 256 * sizeof(u16));
    int*    ssrc = (int*)carve((size_t)E * sizeof(int));
    int*    rowp = (int*)carve((size_t)(N + 1) * sizeof(int));
    int*    deg  = (int*)carve((size_t)N * sizeof(int));
    int*    cur  = (int*)carve((size_t)N * sizeof(int));
    int*    part = (int*)carve((size_t)128 * sizeof(int));
    float*  k3   = (float*)carve((size_t)N * sizeof(float));
    float2* qv3  = (float2*)carve((size_t)N * sizeof(float2));
    float*  s3   = (float*)carve((size_t)N * sizeof(float));

    // --- CSR build ---
    hipMemsetAsync(deg, 0, (size_t)N * sizeof(int), stream);
    hipMemsetAsync(cur, 0, (size_t)N * sizeof(int), stream);
    hist_k<<<2048, 256, 0, stream>>>(dst, deg, E);
    int nb = (N + 1023) / 1024;  // 98
    scan_part_k<<<nb, 256, 0, stream>>>(deg, part, N);
    scan_tops_k<<<1, 128, 0, stream>>>(part, nb);
    scan_emit_k<<<nb, 256, 0, stream>>>(deg, part, rowp, N, E);
    scatter_k<<<2048, 256, 0, stream>>>(src, dst, rowp, cur, ssrc, E);

    // --- weights + x cast ---
    P8 wp;
    wp.p[0] = (const float*)d_in[2];  wp.p[1] = (const float*)d_in[3];
    wp.p[2] = (const float*)d_in[4];  wp.p[3] = (const float*)d_in[5];
    wp.p[4] = (const float*)d_in[7];  wp.p[5] = (const float*)d_in[8];
    wp.p[6] = (const float*)d_in[9];  wp.p[7] = (const float*)d_in[10];
    transpose_w<<<8, 256, 0, stream>>>(wp, Wt);
    cast_f2b<<<1024, 256, 0, stream>>>(x0, bufX, N * 128 / 4);

    int gb = (N + 127) / 128;

    // layer 1
    gemm_kqvs<<<gb, 256, 0, stream>>>(bufX, Wt, (const float*)d_in[6], KS, QV, N);
    edge_csr2<0><<<2048, 256, 0, stream>>>(rowp, ssrc, KS, QV, bufX,
        nullptr, nullptr, nullptr, nullptr, nullptr, nullptr, nullptr, nullptr, N);
    // layer 2 (+ fused layer-3 GEMV)
    gemm_kqvs<<<gb, 256, 0, stream>>>(bufX, Wt + 4 * 16384, (const float*)d_in[11], KS, QV, N);
    edge_csr2<1><<<2048, 256, 0, stream>>>(rowp, ssrc, KS, QV, nullptr,
        (const float*)d_in[12], (const float*)d_in[13], (const float*)d_in[14],
        (const float*)d_in[15], (const float*)d_in[16],
        k3, qv3, s3, N);
    // layer 3 edge pass -> d_out
    edge3_csr<<<1024, 256, 0, stream>>>(rowp, ssrc, k3, qv3, s3, (float*)d_out, N);
}